// Round 1
// baseline (505.856 us; speedup 1.0000x reference)
//
#include <hip/hip_runtime.h>
#include <cmath>

#define TPB 256

// ---------- workspace layout (float index units unless noted) ----------
#define OFF_W1 16        // 500 floats
#define OFF_B1 520       // 20
#define OFF_W2 544       // 25000
#define OFF_B2 25552     // 50
#define OFF_W3 25616     // 400000
#define OFF_B3 425616    // 500  (ends 426116 floats = 1.70 MB)
#define Q1_BYTE_OFF 2097152ULL   // uint8 regions start at 2 MB

// quant constants (all scale_next zero-points are 0; layer-1 input zp = 36)
#define S_X1 (3.5f/255.0f)
#define ZP_X1 36.0f
#define S_N1 (6.0f/255.0f)
#define S_N2 (8.0f/255.0f)
#define S_N3 (10.0f/255.0f)

// monotone float<->uint map for atomic min/max on floats
__device__ inline unsigned int enc_f(float f){
    unsigned int u = __float_as_uint(f);
    return (u & 0x80000000u) ? ~u : (u | 0x80000000u);
}
__device__ inline float dec_f(unsigned int e){
    unsigned int u = (e & 0x80000000u) ? (e & 0x7fffffffu) : ~e;
    return __uint_as_float(u);
}

__device__ inline void sczp(float mn, float mx, float& s, float& zp){
    s = (mx - mn) / 255.0f;
    zp = truncf(fminf(fmaxf(0.0f - mn / s, 0.0f), 255.0f));
}
__device__ inline float qclip(float x, float s, float zp){
    return rintf(fminf(fmaxf(zp + x / s, 0.0f), 255.0f));
}

__global__ void k_init(unsigned int* enc){
    int i = threadIdx.x;
    if (i < 6){ enc[2*i] = 0xFFFFFFFFu; enc[2*i+1] = 0u; }
}

__global__ __launch_bounds__(TPB) void k_minmax(
        const float* c1w, const float* c1b, const float* c2w, const float* c2b,
        const float* f1w, const float* f1b, unsigned int* enc){
    __shared__ float smn[TPB], smx[TPB];
    int bb = blockIdx.x, tid = threadIdx.x;
    const float* src; int n, t, sub, nsub;
    if      (bb == 0){ src=c1w; n=500;    t=0; sub=0;     nsub=1;  }
    else if (bb == 1){ src=c1b; n=20;     t=1; sub=0;     nsub=1;  }
    else if (bb <  6){ src=c2w; n=25000;  t=2; sub=bb-2;  nsub=4;  }
    else if (bb == 6){ src=c2b; n=50;     t=3; sub=0;     nsub=1;  }
    else if (bb < 71){ src=f1w; n=400000; t=4; sub=bb-7;  nsub=64; }
    else             { src=f1b; n=500;    t=5; sub=0;     nsub=1;  }
    float mn = INFINITY, mx = -INFINITY;
    for (int i = sub*TPB + tid; i < n; i += nsub*TPB){
        float v = src[i]; mn = fminf(mn, v); mx = fmaxf(mx, v);
    }
    smn[tid] = mn; smx[tid] = mx; __syncthreads();
    for (int s = TPB/2; s > 0; s >>= 1){
        if (tid < s){
            smn[tid] = fminf(smn[tid], smn[tid+s]);
            smx[tid] = fmaxf(smx[tid], smx[tid+s]);
        }
        __syncthreads();
    }
    if (tid == 0){
        atomicMin(&enc[2*t],   enc_f(smn[0]));
        atomicMax(&enc[2*t+1], enc_f(smx[0]));
    }
}

__global__ __launch_bounds__(TPB) void k_make_eff(
        const float* c1w, const float* c1b, const float* c2w, const float* c2b,
        const float* f1w, const float* f1b, const unsigned int* enc, float* ws){
    int i = blockIdx.x * TPB + threadIdx.x;
    if (i >= 426070) return;
    if (i < 500){
        float s, zp; sczp(dec_f(enc[0]), dec_f(enc[1]), s, zp);
        float wq = qclip(c1w[i], s, zp);
        ws[OFF_W1 + i] = (S_X1 * s) * (wq - zp);
    } else if (i < 520){
        int j = i - 500;
        float s, zp; sczp(dec_f(enc[2]), dec_f(enc[3]), s, zp);
        float bq = qclip(c1b[j], s, zp);
        ws[OFF_B1 + j] = s * (bq + zp);
    } else if (i < 25520){
        int j = i - 520;
        float s, zp; sczp(dec_f(enc[4]), dec_f(enc[5]), s, zp);
        float wq = qclip(c2w[j], s, zp);
        ws[OFF_W2 + j] = (S_N1 * s) * (wq - zp);     // scale_x of layer2 = 6/255
    } else if (i < 25570){
        int j = i - 25520;
        float s, zp; sczp(dec_f(enc[6]), dec_f(enc[7]), s, zp);
        float bq = qclip(c2b[j], s, zp);
        ws[OFF_B2 + j] = s * (bq + zp);
    } else if (i < 425570){
        int j = i - 25570;
        float s, zp; sczp(dec_f(enc[8]), dec_f(enc[9]), s, zp);
        float wq = qclip(f1w[j], s, zp);
        ws[OFF_W3 + j] = (S_N2 * s) * (wq - zp);     // scale_x of fc1 = 8/255
    } else {
        int j = i - 425570;
        float s, zp; sczp(dec_f(enc[10]), dec_f(enc[11]), s, zp);
        float bq = qclip(f1b[j], s, zp);
        ws[OFF_B3 + j] = s * (bq + zp);
    }
}

// conv1 (1->20ch, 5x5, 28->24) + input quant + 2x2 maxpool + requant -> q1p[B][20][12][12] u8
__global__ __launch_bounds__(TPB) void k_conv1(const float* x, const float* ws, unsigned char* q1p){
    __shared__ float xs[784];
    __shared__ float wsm[500];
    __shared__ float bsm[20];
    int b = blockIdx.x, tid = threadIdx.x;
    const float* xb = x + (size_t)b * 784;
    for (int i = tid; i < 784; i += TPB){
        float v = xb[i];
        float q = rintf(fminf(fmaxf(ZP_X1 + v / S_X1, 0.0f), 255.0f));
        xs[i] = q - ZP_X1;                 // X = q - zp
    }
    for (int i = tid; i < 500; i += TPB) wsm[i] = ws[OFF_W1 + i];
    if (tid < 20) bsm[tid] = ws[OFF_B1 + tid];
    __syncthreads();
    for (int po = tid; po < 20*144; po += TPB){
        int co = po / 144, r = po - co*144;
        int ph = r / 12, pw = r - ph*12;
        int oh0 = 2*ph, ow0 = 2*pw;
        float xv[36];
        #pragma unroll
        for (int rr = 0; rr < 6; ++rr)
            #pragma unroll
            for (int cc = 0; cc < 6; ++cc)
                xv[rr*6+cc] = xs[(oh0+rr)*28 + ow0 + cc];
        float wv[25];
        #pragma unroll
        for (int k = 0; k < 25; ++k) wv[k] = wsm[co*25 + k];
        float bias = bsm[co];
        float qmax = 0.0f;
        #pragma unroll
        for (int dy = 0; dy < 2; ++dy)
            #pragma unroll
            for (int dx = 0; dx < 2; ++dx){
                float acc = 0.0f;
                #pragma unroll
                for (int kh = 0; kh < 5; ++kh)
                    #pragma unroll
                    for (int kw = 0; kw < 5; ++kw)
                        acc = fmaf(xv[(dy+kh)*6 + dx+kw], wv[kh*5+kw], acc);
                float y = fmaxf((acc + bias) / S_N1, 0.0f);   // relu(conv/scale + zp0)
                float q = fmodf(rintf(y), 256.0f);            // .byte() wrap
                qmax = fmaxf(qmax, q);
            }
        q1p[(size_t)b*2880 + po] = (unsigned char)qmax;
    }
}

// conv2 (20->50ch, 5x5, 12->8) + 2x2 maxpool + requant -> q2p[B][800] u8 (layout co*16+ph*4+pw)
__global__ __launch_bounds__(TPB) void k_conv2(const unsigned char* q1p, const float* ws, unsigned char* q2p){
    __shared__ float xs[2880];
    __shared__ float bsm[50];
    int b = blockIdx.x, tid = threadIdx.x;
    for (int i = tid; i < 2880; i += TPB) xs[i] = (float)q1p[(size_t)b*2880 + i];
    if (tid < 50) bsm[tid] = ws[OFF_B2 + tid];
    __syncthreads();
    int pos = tid & 15, cg = tid >> 4;       // pos: (ph,pw), cg: channel group
    int ph = pos >> 2, pw = pos & 3;
    float acc[4][4];
    #pragma unroll
    for (int j = 0; j < 4; ++j)
        #pragma unroll
        for (int p = 0; p < 4; ++p) acc[j][p] = 0.0f;
    for (int ci = 0; ci < 20; ++ci){
        float xv[36];
        int base = ci*144 + (2*ph)*12 + 2*pw;
        #pragma unroll
        for (int rr = 0; rr < 6; ++rr)
            #pragma unroll
            for (int cc = 0; cc < 6; ++cc)
                xv[rr*6+cc] = xs[base + rr*12 + cc];
        #pragma unroll
        for (int j = 0; j < 4; ++j){
            int co = cg + 16*j;
            if (co < 50){
                const float* wp = ws + OFF_W2 + (co*20 + ci)*25;
                float wv[25];
                #pragma unroll
                for (int k = 0; k < 25; ++k) wv[k] = wp[k];
                #pragma unroll
                for (int dy = 0; dy < 2; ++dy)
                    #pragma unroll
                    for (int dx = 0; dx < 2; ++dx){
                        float a = acc[j][dy*2+dx];
                        #pragma unroll
                        for (int kh = 0; kh < 5; ++kh)
                            #pragma unroll
                            for (int kw = 0; kw < 5; ++kw)
                                a = fmaf(xv[(dy+kh)*6 + dx+kw], wv[kh*5+kw], a);
                        acc[j][dy*2+dx] = a;
                    }
            }
        }
    }
    #pragma unroll
    for (int j = 0; j < 4; ++j){
        int co = cg + 16*j;
        if (co < 50){
            float bias = bsm[co];
            float qmax = 0.0f;
            #pragma unroll
            for (int p = 0; p < 4; ++p){
                float y = fmaxf((acc[j][p] + bias) / S_N2, 0.0f);
                float q = fmodf(rintf(y), 256.0f);
                qmax = fmaxf(qmax, q);
            }
            q2p[(size_t)b*800 + co*16 + pos] = (unsigned char)qmax;
        }
    }
}

// fc1: [B,800] x [500,800]^T + requant -> q3[B][500] u8.  64x64 tiles, 4x4 micro.
__global__ __launch_bounds__(TPB) void k_fc1(const unsigned char* q2p, const float* ws,
                                             unsigned char* q3, int B){
    __shared__ float As[64][17];
    __shared__ float Bs[64][17];
    int tid = threadIdx.x;
    int n0 = blockIdx.x * 64;
    int b0 = blockIdx.y * 64;
    int tx = tid & 15, ty = tid >> 4;
    float acc[4][4];
    #pragma unroll
    for (int i = 0; i < 4; ++i)
        #pragma unroll
        for (int j = 0; j < 4; ++j) acc[i][j] = 0.0f;
    for (int k0 = 0; k0 < 800; k0 += 16){
        #pragma unroll
        for (int r = 0; r < 4; ++r){
            int idx = r*256 + tid;
            int row = idx >> 4, kk = idx & 15;
            int rb = b0 + row;
            As[row][kk] = (rb < B) ? (float)q2p[(size_t)rb*800 + k0 + kk] : 0.0f;
            int n = n0 + row;
            Bs[row][kk] = (n < 500) ? ws[OFF_W3 + (size_t)n*800 + k0 + kk] : 0.0f;
        }
        __syncthreads();
        #pragma unroll
        for (int k = 0; k < 16; ++k){
            float av[4], bv[4];
            #pragma unroll
            for (int i = 0; i < 4; ++i) av[i] = As[ty*4+i][k];
            #pragma unroll
            for (int j = 0; j < 4; ++j) bv[j] = Bs[tx*4+j][k];
            #pragma unroll
            for (int i = 0; i < 4; ++i)
                #pragma unroll
                for (int j = 0; j < 4; ++j)
                    acc[i][j] = fmaf(av[i], bv[j], acc[i][j]);
        }
        __syncthreads();
    }
    #pragma unroll
    for (int i = 0; i < 4; ++i){
        int row = b0 + ty*4 + i;
        if (row < B){
            #pragma unroll
            for (int j = 0; j < 4; ++j){
                int n = n0 + tx*4 + j;
                if (n < 500){
                    float y = fmaxf((acc[i][j] + ws[OFF_B3 + n]) / S_N3, 0.0f);
                    float q = fmodf(rintf(y), 256.0f);
                    q3[(size_t)row*500 + n] = (unsigned char)q;
                }
            }
        }
    }
}

// fc2 (dequant -> [B,500]x[10,500]^T + bias) + log_softmax -> out[B][10] f32. One wave per row.
__global__ __launch_bounds__(TPB) void k_fc2(const unsigned char* q3, const float* w2,
                                             const float* b2, float* out, int B){
    int tid = threadIdx.x;
    int lane = tid & 63, wv = tid >> 6;
    int b = blockIdx.x * 4 + wv;
    if (b >= B) return;
    float acc[10];
    #pragma unroll
    for (int c = 0; c < 10; ++c) acc[c] = 0.0f;
    for (int k = lane; k < 500; k += 64){
        float xf = S_N3 * (float)q3[(size_t)b*500 + k];   // s*(q - 0)
        #pragma unroll
        for (int c = 0; c < 10; ++c)
            acc[c] = fmaf(xf, w2[c*500 + k], acc[c]);
    }
    #pragma unroll
    for (int off = 32; off > 0; off >>= 1)
        #pragma unroll
        for (int c = 0; c < 10; ++c)
            acc[c] += __shfl_xor(acc[c], off);
    float lg[10], m = -INFINITY;
    #pragma unroll
    for (int c = 0; c < 10; ++c){ lg[c] = acc[c] + b2[c]; m = fmaxf(m, lg[c]); }
    float sum = 0.0f;
    #pragma unroll
    for (int c = 0; c < 10; ++c) sum += expf(lg[c] - m);
    float ls = logf(sum);
    if (lane < 10) out[(size_t)b*10 + lane] = lg[lane] - m - ls;
}

extern "C" void kernel_launch(void* const* d_in, const int* in_sizes, int n_in,
                              void* d_out, int out_size, void* d_ws, size_t ws_size,
                              hipStream_t stream){
    const float* x   = (const float*)d_in[0];
    const float* c1w = (const float*)d_in[1];
    const float* c1b = (const float*)d_in[2];
    const float* c2w = (const float*)d_in[3];
    const float* c2b = (const float*)d_in[4];
    const float* f1w = (const float*)d_in[5];
    const float* f1b = (const float*)d_in[6];
    const float* f2w = (const float*)d_in[7];
    const float* f2b = (const float*)d_in[8];
    int B = in_sizes[0] / 784;

    float* ws = (float*)d_ws;
    unsigned int* enc = (unsigned int*)d_ws;
    unsigned char* q1p = (unsigned char*)d_ws + Q1_BYTE_OFF;
    unsigned char* q2p = q1p + (size_t)B * 2880;
    unsigned char* q3  = q2p + (size_t)B * 800;
    float* out = (float*)d_out;

    k_init<<<1, 64, 0, stream>>>(enc);
    k_minmax<<<72, TPB, 0, stream>>>(c1w, c1b, c2w, c2b, f1w, f1b, enc);
    k_make_eff<<<(426070 + TPB - 1)/TPB, TPB, 0, stream>>>(c1w, c1b, c2w, c2b, f1w, f1b, enc, ws);
    k_conv1<<<B, TPB, 0, stream>>>(x, ws, q1p);
    k_conv2<<<B, TPB, 0, stream>>>(q1p, ws, q2p);
    dim3 g_fc1(8, (B + 63)/64);
    k_fc1<<<g_fc1, TPB, 0, stream>>>(q2p, ws, q3, B);
    k_fc2<<<(B + 3)/4, TPB, 0, stream>>>(q3, f2w, f2b, out, B);
}

// Round 2
// 236.481 us; speedup vs baseline: 2.1391x; 2.1391x over previous
//
#include <hip/hip_runtime.h>
#include <cmath>

#define TPB 256
typedef float floatx4 __attribute__((ext_vector_type(4)));
typedef __bf16 bf16x8 __attribute__((ext_vector_type(8)));
typedef unsigned short ushort8 __attribute__((ext_vector_type(8)));
typedef unsigned short ushort_t;

// ---------- workspace layout ----------
// float units: [0]=sc2 (S_N1*s_w2), [1]=sc3 (S_N2*s_w3)
// uint units 4..15: enc min/max (6 pairs)
#define OFF_W1 16        // 500 f32 conv1 W_eff
#define OFF_B1 520       // 20  f32
#define OFF_B2 544       // 50  f32
#define OFF_B3 600       // 500 f32
#define W2BF_BYTE 8192       // [20][64][32] u16 int weights (conv2)
#define W3BF_BYTE 131072     // [512][800]  u16 int weights (fc1)
#define Q1_BYTE  1048576ULL  // [B][20][12][12] bf16
#define Q2_BYTE  25165824ULL // [B][800] bf16
#define Q3_BYTE  33554432ULL // [B][500] u8

#define S_X1 (3.5f/255.0f)
#define ZP_X1 36.0f
#define S_N1 (6.0f/255.0f)
#define S_N2 (8.0f/255.0f)
#define S_N3 (10.0f/255.0f)

__device__ inline unsigned int enc_f(float f){
    unsigned int u = __float_as_uint(f);
    return (u & 0x80000000u) ? ~u : (u | 0x80000000u);
}
__device__ inline float dec_f(unsigned int e){
    unsigned int u = (e & 0x80000000u) ? (e & 0x7fffffffu) : ~e;
    return __uint_as_float(u);
}
__device__ inline void sczp(float mn, float mx, float& s, float& zp){
    s = (mx - mn) / 255.0f;
    zp = truncf(fminf(fmaxf(0.0f - mn / s, 0.0f), 255.0f));
}
__device__ inline float qclip(float x, float s, float zp){
    return rintf(fminf(fmaxf(zp + x / s, 0.0f), 255.0f));
}
// exact bf16 bits for integer-valued floats |v| < 256
__device__ inline ushort_t bfbits(float v){
    return (ushort_t)(__float_as_uint(v) >> 16);
}

__global__ void k_init(unsigned int* enc){
    int i = threadIdx.x;
    if (i < 6){ enc[2*i] = 0xFFFFFFFFu; enc[2*i+1] = 0u; }
}

__global__ __launch_bounds__(TPB) void k_minmax(
        const float* c1w, const float* c1b, const float* c2w, const float* c2b,
        const float* f1w, const float* f1b, unsigned int* enc){
    __shared__ float smn[TPB], smx[TPB];
    int bb = blockIdx.x, tid = threadIdx.x;
    const float* src; int n, t, sub, nsub;
    if      (bb == 0){ src=c1w; n=500;    t=0; sub=0;     nsub=1;  }
    else if (bb == 1){ src=c1b; n=20;     t=1; sub=0;     nsub=1;  }
    else if (bb <  6){ src=c2w; n=25000;  t=2; sub=bb-2;  nsub=4;  }
    else if (bb == 6){ src=c2b; n=50;     t=3; sub=0;     nsub=1;  }
    else if (bb < 71){ src=f1w; n=400000; t=4; sub=bb-7;  nsub=64; }
    else             { src=f1b; n=500;    t=5; sub=0;     nsub=1;  }
    float mn = INFINITY, mx = -INFINITY;
    for (int i = sub*TPB + tid; i < n; i += nsub*TPB){
        float v = src[i]; mn = fminf(mn, v); mx = fmaxf(mx, v);
    }
    smn[tid] = mn; smx[tid] = mx; __syncthreads();
    for (int s = TPB/2; s > 0; s >>= 1){
        if (tid < s){
            smn[tid] = fminf(smn[tid], smn[tid+s]);
            smx[tid] = fmaxf(smx[tid], smx[tid+s]);
        }
        __syncthreads();
    }
    if (tid == 0){
        atomicMin(&enc[2*t],   enc_f(smn[0]));
        atomicMax(&enc[2*t+1], enc_f(smx[0]));
    }
}

#define N_EFF 451632
__global__ __launch_bounds__(TPB) void k_make_eff(
        const float* c1w, const float* c1b, const float* c2w, const float* c2b,
        const float* f1w, const float* f1b, const unsigned int* enc,
        float* ws, ushort_t* w2bf, ushort_t* w3bf){
    int i = blockIdx.x * TPB + threadIdx.x;
    if (i >= N_EFF) return;
    if (i < 500){
        float s, zp; sczp(dec_f(enc[0]), dec_f(enc[1]), s, zp);
        ws[OFF_W1 + i] = (S_X1 * s) * (qclip(c1w[i], s, zp) - zp);
    } else if (i < 520){
        int j = i - 500;
        float s, zp; sczp(dec_f(enc[2]), dec_f(enc[3]), s, zp);
        ws[OFF_B1 + j] = s * (qclip(c1b[j], s, zp) + zp);
    } else if (i < 41480){           // w2bf: [ci][co(64)][k(32)]
        int j = i - 520;
        int ci = j >> 11, r = j & 2047, co = r >> 5, k = r & 31;
        float v = 0.0f;
        if (co < 50 && k < 25){
            float s, zp; sczp(dec_f(enc[4]), dec_f(enc[5]), s, zp);
            v = qclip(c2w[(co*20 + ci)*25 + k], s, zp) - zp;
        }
        w2bf[j] = bfbits(v);
    } else if (i < 41530){
        int j = i - 41480;
        float s, zp; sczp(dec_f(enc[6]), dec_f(enc[7]), s, zp);
        ws[OFF_B2 + j] = s * (qclip(c2b[j], s, zp) + zp);
    } else if (i < 451130){          // w3bf: [n(512)][k(800)]
        int j = i - 41530;
        int n = j / 800, k = j - 800*n;
        float v = 0.0f;
        if (n < 500){
            float s, zp; sczp(dec_f(enc[8]), dec_f(enc[9]), s, zp);
            v = qclip(f1w[n*800 + k], s, zp) - zp;
        }
        w3bf[j] = bfbits(v);
    } else if (i < 451630){
        int j = i - 451130;
        float s, zp; sczp(dec_f(enc[10]), dec_f(enc[11]), s, zp);
        ws[OFF_B3 + j] = s * (qclip(f1b[j], s, zp) + zp);
    } else if (i == 451630){
        float s, zp; sczp(dec_f(enc[4]), dec_f(enc[5]), s, zp);
        ws[0] = S_N1 * s;            // conv2 combined scale
    } else {
        float s, zp; sczp(dec_f(enc[8]), dec_f(enc[9]), s, zp);
        ws[1] = S_N2 * s;            // fc1 combined scale
    }
}

// conv1 (VALU) + quant + pool -> q1bf[B][20][12][12] bf16 ints
__global__ __launch_bounds__(TPB) void k_conv1(const float* x, const float* ws, ushort_t* q1bf){
    __shared__ float xs[784];
    __shared__ float wsm[500];
    __shared__ float bsm[20];
    int b = blockIdx.x, tid = threadIdx.x;
    const float* xb = x + (size_t)b * 784;
    for (int i = tid; i < 784; i += TPB){
        float v = xb[i];
        float q = rintf(fminf(fmaxf(ZP_X1 + v / S_X1, 0.0f), 255.0f));
        xs[i] = q - ZP_X1;
    }
    for (int i = tid; i < 500; i += TPB) wsm[i] = ws[OFF_W1 + i];
    if (tid < 20) bsm[tid] = ws[OFF_B1 + tid];
    __syncthreads();
    for (int po = tid; po < 20*144; po += TPB){
        int co = po / 144, r = po - co*144;
        int ph = r / 12, pw = r - ph*12;
        int oh0 = 2*ph, ow0 = 2*pw;
        float xv[36];
        #pragma unroll
        for (int rr = 0; rr < 6; ++rr)
            #pragma unroll
            for (int cc = 0; cc < 6; ++cc)
                xv[rr*6+cc] = xs[(oh0+rr)*28 + ow0 + cc];
        float wv[25];
        #pragma unroll
        for (int k = 0; k < 25; ++k) wv[k] = wsm[co*25 + k];
        float bias = bsm[co];
        float qmax = 0.0f;
        #pragma unroll
        for (int dy = 0; dy < 2; ++dy)
            #pragma unroll
            for (int dx = 0; dx < 2; ++dx){
                float acc = 0.0f;
                #pragma unroll
                for (int kh = 0; kh < 5; ++kh)
                    #pragma unroll
                    for (int kw = 0; kw < 5; ++kw)
                        acc = fmaf(xv[(dy+kh)*6 + dx+kw], wv[kh*5+kw], acc);
                float y = fmaxf((acc + bias) / S_N1, 0.0f);
                float q = fmodf(rintf(y), 256.0f);
                qmax = fmaxf(qmax, q);
            }
        q1bf[(size_t)b*2880 + po] = bfbits(qmax);
    }
}

// conv2 via bf16 MFMA implicit GEMM. One image per block. M=64 pos, N=64(50), K=20x32.
// + quantize + 2x2 pool -> q2bf[B][800] bf16 ints (k = co*16 + ph*4 + pw)
__global__ __launch_bounds__(TPB) void k_conv2(const ushort_t* q1bf, const ushort_t* w2bf,
                                               const float* ws, ushort_t* q2bf){
    __shared__ ushort_t xs[2880];
    __shared__ ushort_t Ab[2][64*40];
    int b = blockIdx.x, tid = threadIdx.x;
    int lane = tid & 63, wv = tid >> 6;
    int ln = lane & 15, quad = lane >> 4;
    int n0 = wv * 16;

    // load image (bf16 ints) coalesced as dwords
    const unsigned int* src32 = (const unsigned int*)(q1bf + (size_t)b*2880);
    unsigned int* xs32 = (unsigned int*)xs;
    for (int i = tid; i < 1440; i += TPB) xs32[i] = src32[i];
    // zero pad region k=25..31 of both im2col buffers
    for (int i = tid; i < 448; i += TPB){
        int p = i / 7, k = 25 + (i - 7*p);
        Ab[0][p*40 + k] = 0; Ab[1][p*40 + k] = 0;
    }
    // per-thread im2col offsets (ci-invariant)
    int dstoff[7], srcoff[7];
    #pragma unroll
    for (int t = 0; t < 7; ++t){
        int e = tid + t*TPB;
        if (e < 1600){
            int p = e / 25, k = e - 25*p;
            int kh = k / 5, kw = k - 5*kh;
            int oh = p >> 3, ow = p & 7;
            dstoff[t] = p*40 + k;
            srcoff[t] = (oh + kh)*12 + (ow + kw);
        } else dstoff[t] = -1;
    }
    __syncthreads();
    // build ci=0
    #pragma unroll
    for (int t = 0; t < 7; ++t)
        if (dstoff[t] >= 0) Ab[0][dstoff[t]] = xs[srcoff[t]];
    __syncthreads();

    floatx4 acc[4];
    #pragma unroll
    for (int mt = 0; mt < 4; ++mt) acc[mt] = (floatx4){0.f,0.f,0.f,0.f};

    for (int ci = 0; ci < 20; ++ci){
        const ushort_t* cur = &Ab[ci & 1][0];
        if (ci + 1 < 20){
            ushort_t* nxt = &Ab[(ci + 1) & 1][0];
            int base = (ci + 1) * 144;
            #pragma unroll
            for (int t = 0; t < 7; ++t)
                if (dstoff[t] >= 0) nxt[dstoff[t]] = xs[base + srcoff[t]];
        }
        ushort8 bw = *(const ushort8*)(w2bf + ci*2048 + (n0 + ln)*32 + quad*8);
        bf16x8 bfr = __builtin_bit_cast(bf16x8, bw);
        #pragma unroll
        for (int mt = 0; mt < 4; ++mt){
            ushort8 aw = *(const ushort8*)(cur + (16*mt + ln)*40 + quad*8);
            acc[mt] = __builtin_amdgcn_mfma_f32_16x16x32_bf16(
                          __builtin_bit_cast(bf16x8, aw), bfr, acc[mt], 0, 0, 0);
        }
        __syncthreads();
    }

    // epilogue: quantize each of 64 positions, then 2x2 pool, write bf16
    float sc2 = ws[0];
    int n = n0 + ln;
    float bias = (n < 50) ? ws[OFF_B2 + n] : 0.0f;
    #pragma unroll
    for (int mt = 0; mt < 4; ++mt){
        float q[4];
        #pragma unroll
        for (int r = 0; r < 4; ++r){
            float y = fmaxf((acc[mt][r] * sc2 + bias) / S_N2, 0.0f);
            q[r] = fmodf(rintf(y), 256.0f);
        }
        float h0 = fmaxf(q[0], q[1]), h1 = fmaxf(q[2], q[3]);
        float v0 = fmaxf(h0, __shfl_xor(h0, 32));
        float v1 = fmaxf(h1, __shfl_xor(h1, 32));
        if (quad < 2 && n < 50){
            size_t base = (size_t)b*800 + n*16 + mt*4 + quad*2;
            q2bf[base]     = bfbits(v0);
            q2bf[base + 1] = bfbits(v1);
        }
    }
}

// fc1 via bf16 MFMA GEMM: [B,800] x [512,800]^T, tile 64x64, K-chunk 32, dbuf LDS.
__global__ __launch_bounds__(TPB) void k_fc1(const ushort_t* q2bf, const ushort_t* w3bf,
                                             const float* ws, unsigned char* q3, int B){
    __shared__ ushort_t As[2][64*40];
    int tid = threadIdx.x;
    int n0b = blockIdx.x * 64;
    int b0  = blockIdx.y * 64;
    int lane = tid & 63, wv = tid >> 6;
    int ln = lane & 15, quad = lane >> 4;
    int n0 = n0b + wv*16;
    int lrow = tid >> 2, lk = (tid & 3) * 8;
    const ushort_t* asrc = q2bf + (size_t)(b0 + lrow)*800 + lk;
    ushort_t* adst0 = &As[0][0] + lrow*40 + lk;
    ushort_t* adst1 = &As[1][0] + lrow*40 + lk;

    floatx4 acc[4];
    #pragma unroll
    for (int mt = 0; mt < 4; ++mt) acc[mt] = (floatx4){0.f,0.f,0.f,0.f};

    // prologue: chunk 0
    *(ushort8*)adst0 = *(const ushort8*)asrc;
    __syncthreads();

    for (int c = 0; c < 25; ++c){
        const ushort_t* cur = &As[c & 1][0];
        ushort8 tn;
        bool pf = (c + 1 < 25);
        if (pf) tn = *(const ushort8*)(asrc + (c + 1)*32);
        ushort8 bw = *(const ushort8*)(w3bf + (size_t)(n0 + ln)*800 + c*32 + quad*8);
        bf16x8 bfr = __builtin_bit_cast(bf16x8, bw);
        #pragma unroll
        for (int mt = 0; mt < 4; ++mt){
            ushort8 aw = *(const ushort8*)(cur + (16*mt + ln)*40 + quad*8);
            acc[mt] = __builtin_amdgcn_mfma_f32_16x16x32_bf16(
                          __builtin_bit_cast(bf16x8, aw), bfr, acc[mt], 0, 0, 0);
        }
        if (pf) *(ushort8*)(((c + 1) & 1) ? adst1 : adst0) = tn;
        __syncthreads();
    }

    float sc3 = ws[1];
    int n = n0 + ln;
    if (n < 500){
        float bias = ws[OFF_B3 + n];
        #pragma unroll
        for (int mt = 0; mt < 4; ++mt){
            #pragma unroll
            for (int r = 0; r < 4; ++r){
                int m = 16*mt + 4*quad + r;
                float y = fmaxf((acc[mt][r] * sc3 + bias) / S_N3, 0.0f);
                float q = fmodf(rintf(y), 256.0f);
                q3[(size_t)(b0 + m)*500 + n] = (unsigned char)q;
            }
        }
    }
}

// fc2 (dequant + [B,500]x[10,500]^T + bias) + log_softmax. 16 rows/block, w2 in LDS.
__global__ __launch_bounds__(TPB) void k_fc2(const unsigned char* q3, const float* w2,
                                             const float* b2, float* out, int B){
    __shared__ float w2s[5000];
    __shared__ float b2s[10];
    int tid = threadIdx.x;
    for (int i = tid; i < 5000; i += TPB) w2s[i] = w2[i];
    if (tid < 10) b2s[tid] = b2[tid];
    __syncthreads();
    int lane = tid & 63, wv = tid >> 6;
    for (int rr = 0; rr < 4; ++rr){
        int b = blockIdx.x*16 + wv*4 + rr;
        if (b >= B) break;
        float acc[10];
        #pragma unroll
        for (int c = 0; c < 10; ++c) acc[c] = 0.0f;
        for (int k = lane; k < 500; k += 64){
            float xf = S_N3 * (float)q3[(size_t)b*500 + k];
            #pragma unroll
            for (int c = 0; c < 10; ++c)
                acc[c] = fmaf(xf, w2s[c*500 + k], acc[c]);
        }
        #pragma unroll
        for (int off = 32; off > 0; off >>= 1)
            #pragma unroll
            for (int c = 0; c < 10; ++c)
                acc[c] += __shfl_xor(acc[c], off);
        float lg[10], m = -INFINITY;
        #pragma unroll
        for (int c = 0; c < 10; ++c){ lg[c] = acc[c] + b2s[c]; m = fmaxf(m, lg[c]); }
        float sum = 0.0f;
        #pragma unroll
        for (int c = 0; c < 10; ++c) sum += expf(lg[c] - m);
        float ls = logf(sum);
        if (lane < 10) out[(size_t)b*10 + lane] = lg[lane] - m - ls;
    }
}

extern "C" void kernel_launch(void* const* d_in, const int* in_sizes, int n_in,
                              void* d_out, int out_size, void* d_ws, size_t ws_size,
                              hipStream_t stream){
    const float* x   = (const float*)d_in[0];
    const float* c1w = (const float*)d_in[1];
    const float* c1b = (const float*)d_in[2];
    const float* c2w = (const float*)d_in[3];
    const float* c2b = (const float*)d_in[4];
    const float* f1w = (const float*)d_in[5];
    const float* f1b = (const float*)d_in[6];
    const float* f2w = (const float*)d_in[7];
    const float* f2b = (const float*)d_in[8];
    int B = in_sizes[0] / 784;

    float* ws = (float*)d_ws;
    unsigned int* enc = (unsigned int*)d_ws + 4;
    ushort_t* w2bf = (ushort_t*)((char*)d_ws + W2BF_BYTE);
    ushort_t* w3bf = (ushort_t*)((char*)d_ws + W3BF_BYTE);
    ushort_t* q1bf = (ushort_t*)((char*)d_ws + Q1_BYTE);
    ushort_t* q2bf = (ushort_t*)((char*)d_ws + Q2_BYTE);
    unsigned char* q3 = (unsigned char*)d_ws + Q3_BYTE;
    float* out = (float*)d_out;

    k_init<<<1, 64, 0, stream>>>(enc);
    k_minmax<<<72, TPB, 0, stream>>>(c1w, c1b, c2w, c2b, f1w, f1b, enc);
    k_make_eff<<<(N_EFF + TPB - 1)/TPB, TPB, 0, stream>>>(c1w, c1b, c2w, c2b, f1w, f1b, enc, ws, w2bf, w3bf);
    k_conv1<<<B, TPB, 0, stream>>>(x, ws, q1bf);
    k_conv2<<<B, TPB, 0, stream>>>(q1bf, w2bf, ws, q2bf);
    dim3 g_fc1(8, B/64);
    k_fc1<<<g_fc1, TPB, 0, stream>>>(q2bf, w3bf, ws, q3, B);
    k_fc2<<<(B + 15)/16, TPB, 0, stream>>>(q3, f2w, f2b, out, B);
}

// Round 3
// 216.799 us; speedup vs baseline: 2.3333x; 1.0908x over previous
//
#include <hip/hip_runtime.h>
#include <cmath>

#define TPB 256
typedef float floatx4 __attribute__((ext_vector_type(4)));
typedef __bf16 bf16x8 __attribute__((ext_vector_type(8)));
typedef unsigned short ushort8 __attribute__((ext_vector_type(8)));
typedef unsigned short ushort_t;

// ---------- workspace layout ----------
// float units: [0]=sc2 (S_N1*s_w2), [1]=sc3 (S_N2*s_w3), [2]=K1 (S_X1*s_w1/S_N1)
// uint units 4..15: enc min/max (6 pairs)
#define OFF_B1 520       // 20  f32  (pre-divided by S_N1)
#define OFF_B2 544       // 50  f32
#define OFF_B3 600       // 500 f32
#define W1BF_BYTE 6144       // [32][32] u16 int weights (conv1)
#define W2BF_BYTE 8192       // [20][64][32] u16 int weights (conv2)
#define W3BF_BYTE 131072     // [512][800]  u16 int weights (fc1)
#define Q1_BYTE  1048576ULL  // [B][20][12][12] bf16
#define Q2_BYTE  25165824ULL // [B][800] bf16
#define Q3_BYTE  33554432ULL // [B][500] u8

#define S_X1 (3.5f/255.0f)
#define ZP_X1 36.0f
#define S_N1 (6.0f/255.0f)
#define S_N2 (8.0f/255.0f)
#define S_N3 (10.0f/255.0f)

__device__ inline unsigned int enc_f(float f){
    unsigned int u = __float_as_uint(f);
    return (u & 0x80000000u) ? ~u : (u | 0x80000000u);
}
__device__ inline float dec_f(unsigned int e){
    unsigned int u = (e & 0x80000000u) ? (e & 0x7fffffffu) : ~e;
    return __uint_as_float(u);
}
__device__ inline void sczp(float mn, float mx, float& s, float& zp){
    s = (mx - mn) / 255.0f;
    zp = truncf(fminf(fmaxf(0.0f - mn / s, 0.0f), 255.0f));
}
__device__ inline float qclip(float x, float s, float zp){
    return rintf(fminf(fmaxf(zp + x / s, 0.0f), 255.0f));
}
// exact bf16 bits for integer-valued floats |v| < 256
__device__ inline ushort_t bfbits(float v){
    return (ushort_t)(__float_as_uint(v) >> 16);
}

__global__ void k_init(unsigned int* enc){
    int i = threadIdx.x;
    if (i < 6){ enc[2*i] = 0xFFFFFFFFu; enc[2*i+1] = 0u; }
}

__global__ __launch_bounds__(TPB) void k_minmax(
        const float* c1w, const float* c1b, const float* c2w, const float* c2b,
        const float* f1w, const float* f1b, unsigned int* enc){
    __shared__ float smn[TPB], smx[TPB];
    int bb = blockIdx.x, tid = threadIdx.x;
    const float* src; int n, t, sub, nsub;
    if      (bb == 0){ src=c1w; n=500;    t=0; sub=0;     nsub=1;  }
    else if (bb == 1){ src=c1b; n=20;     t=1; sub=0;     nsub=1;  }
    else if (bb <  6){ src=c2w; n=25000;  t=2; sub=bb-2;  nsub=4;  }
    else if (bb == 6){ src=c2b; n=50;     t=3; sub=0;     nsub=1;  }
    else if (bb < 71){ src=f1w; n=400000; t=4; sub=bb-7;  nsub=64; }
    else             { src=f1b; n=500;    t=5; sub=0;     nsub=1;  }
    float mn = INFINITY, mx = -INFINITY;
    for (int i = sub*TPB + tid; i < n; i += nsub*TPB){
        float v = src[i]; mn = fminf(mn, v); mx = fmaxf(mx, v);
    }
    smn[tid] = mn; smx[tid] = mx; __syncthreads();
    for (int s = TPB/2; s > 0; s >>= 1){
        if (tid < s){
            smn[tid] = fminf(smn[tid], smn[tid+s]);
            smx[tid] = fmaxf(smx[tid], smx[tid+s]);
        }
        __syncthreads();
    }
    if (tid == 0){
        atomicMin(&enc[2*t],   enc_f(smn[0]));
        atomicMax(&enc[2*t+1], enc_f(smx[0]));
    }
}

#define N_EFF 452157
__global__ __launch_bounds__(TPB) void k_make_eff(
        const float* c1w, const float* c1b, const float* c2w, const float* c2b,
        const float* f1w, const float* f1b, const unsigned int* enc,
        float* ws, ushort_t* w1bf, ushort_t* w2bf, ushort_t* w3bf){
    int i = blockIdx.x * TPB + threadIdx.x;
    if (i >= N_EFF) return;
    if (i < 1024){                   // w1bf: [n(32)][k(32)] integer weights
        int n = i >> 5, k = i & 31;
        float v = 0.0f;
        if (n < 20 && k < 25){
            float s, zp; sczp(dec_f(enc[0]), dec_f(enc[1]), s, zp);
            v = qclip(c1w[n*25 + k], s, zp) - zp;
        }
        w1bf[i] = bfbits(v);
    } else if (i < 1044){            // b1 pre-divided by S_N1
        int j = i - 1024;
        float s, zp; sczp(dec_f(enc[2]), dec_f(enc[3]), s, zp);
        ws[OFF_B1 + j] = (s * (qclip(c1b[j], s, zp) + zp)) / S_N1;
    } else if (i < 42004){           // w2bf: [ci][co(64)][k(32)]
        int j = i - 1044;
        int ci = j >> 11, r = j & 2047, co = r >> 5, k = r & 31;
        float v = 0.0f;
        if (co < 50 && k < 25){
            float s, zp; sczp(dec_f(enc[4]), dec_f(enc[5]), s, zp);
            v = qclip(c2w[(co*20 + ci)*25 + k], s, zp) - zp;
        }
        w2bf[j] = bfbits(v);
    } else if (i < 42054){
        int j = i - 42004;
        float s, zp; sczp(dec_f(enc[6]), dec_f(enc[7]), s, zp);
        ws[OFF_B2 + j] = s * (qclip(c2b[j], s, zp) + zp);
    } else if (i < 451654){          // w3bf: [n(512)][k(800)]
        int j = i - 42054;
        int n = j / 800, k = j - 800*n;
        float v = 0.0f;
        if (n < 500){
            float s, zp; sczp(dec_f(enc[8]), dec_f(enc[9]), s, zp);
            v = qclip(f1w[n*800 + k], s, zp) - zp;
        }
        w3bf[j] = bfbits(v);
    } else if (i < 452154){
        int j = i - 451654;
        float s, zp; sczp(dec_f(enc[10]), dec_f(enc[11]), s, zp);
        ws[OFF_B3 + j] = s * (qclip(f1b[j], s, zp) + zp);
    } else if (i == 452154){
        float s, zp; sczp(dec_f(enc[4]), dec_f(enc[5]), s, zp);
        ws[0] = S_N1 * s;            // conv2 combined scale
    } else if (i == 452155){
        float s, zp; sczp(dec_f(enc[8]), dec_f(enc[9]), s, zp);
        ws[1] = S_N2 * s;            // fc1 combined scale
    } else {
        float s, zp; sczp(dec_f(enc[0]), dec_f(enc[1]), s, zp);
        ws[2] = (S_X1 * s) / S_N1;   // conv1 combined scale, pre-divided
    }
}

// conv1 via bf16 MFMA implicit GEMM. One image/block. M=576 pos, N=20 (2 n-tiles), K=25->32.
// A-frag gathered directly from 784-entry LDS image; quant + 2x2 pool -> q1bf[B][20][12][12]
__global__ __launch_bounds__(TPB) void k_conv1(const float* x, const ushort_t* w1bf,
                                               const float* ws, ushort_t* q1bf){
    __shared__ ushort_t xs[784];
    __shared__ unsigned char hb[5760];   // [oh(24)*12+pw][ch(20)] horizontal pool maxes
    int b = blockIdx.x, tid = threadIdx.x;
    int lane = tid & 63, wv = tid >> 6;
    int ln = lane & 15, quad = lane >> 4;

    // quantize input into LDS as bf16-bit ints (q - zp)
    const float* xb = x + (size_t)b * 784;
    for (int i = tid; i < 784; i += TPB){
        float v = xb[i];
        float q = rintf(fminf(fmaxf(ZP_X1 + v / S_X1, 0.0f), 255.0f));
        xs[i] = bfbits(q - ZP_X1);
    }

    // per-lane gather offsets for the 8 k-slots (k = quad*8 + j), k<25 valid
    int offj[8]; bool vj[8];
    #pragma unroll
    for (int j = 0; j < 8; ++j){
        int k = quad*8 + j;
        vj[j] = (k < 25);
        int kh = k / 5, kw = k - 5*kh;
        offj[j] = vj[j] ? (kh*28 + kw) : 0;
    }

    // B-frags for the two n-tiles (ch 0-15, ch 16-19+pad), kept in regs
    ushort8 bw0 = *(const ushort8*)(w1bf + ln*32 + quad*8);
    ushort8 bw1 = *(const ushort8*)(w1bf + (16 + ln)*32 + quad*8);
    bf16x8 bf0 = __builtin_bit_cast(bf16x8, bw0);
    bf16x8 bf1 = __builtin_bit_cast(bf16x8, bw1);

    float K1 = ws[2];
    float B1_0 = ws[OFF_B1 + ln];
    float B1_1 = (ln < 4) ? ws[OFF_B1 + 16 + ln] : 0.0f;
    __syncthreads();

    // each wave: 9 m-tiles (m = wv*144 .. +143)
    for (int i = 0; i < 9; ++i){
        int mt = 9*wv + i;
        int m = mt*16 + ln;
        int oh = m / 24, ow = m - 24*oh;
        int base = oh*28 + ow;
        ushort8 aw;
        #pragma unroll
        for (int j = 0; j < 8; ++j)
            aw[j] = vj[j] ? xs[base + offj[j]] : (ushort_t)0;
        bf16x8 af = __builtin_bit_cast(bf16x8, aw);
        floatx4 z = (floatx4){0.f,0.f,0.f,0.f};
        floatx4 a0 = __builtin_amdgcn_mfma_f32_16x16x32_bf16(af, bf0, z, 0, 0, 0);
        floatx4 a1 = __builtin_amdgcn_mfma_f32_16x16x32_bf16(af, bf1, z, 0, 0, 0);

        // epilogue: quantize, horizontal pool pairs in-reg, stash to LDS
        int m0 = mt*16 + quad*4;
        int oh0 = m0 / 24, owp = (m0 - 24*oh0) >> 1;
        int hbase = (oh0*12 + owp)*20;
        {
            float q[4];
            #pragma unroll
            for (int r = 0; r < 4; ++r){
                float y = fmaxf(fmaf(a0[r], K1, B1_0), 0.0f);
                q[r] = fmodf(rintf(y), 256.0f);
            }
            hb[hbase + ln]      = (unsigned char)fmaxf(q[0], q[1]);
            hb[hbase + 20 + ln] = (unsigned char)fmaxf(q[2], q[3]);
        }
        if (ln < 4){
            float q[4];
            #pragma unroll
            for (int r = 0; r < 4; ++r){
                float y = fmaxf(fmaf(a1[r], K1, B1_1), 0.0f);
                q[r] = fmodf(rintf(y), 256.0f);
            }
            hb[hbase + 16 + ln]      = (unsigned char)fmaxf(q[0], q[1]);
            hb[hbase + 36 + ln]      = (unsigned char)fmaxf(q[2], q[3]);
        }
    }
    __syncthreads();

    // vertical pool + write bf16 ints, layout [ch][12][12]
    for (int o = tid; o < 2880; o += TPB){
        int c = o / 144, r = o - 144*c;
        int ph = r / 12, pw = r - 12*ph;
        unsigned char t_ = hb[((2*ph)*12 + pw)*20 + c];
        unsigned char u_ = hb[((2*ph+1)*12 + pw)*20 + c];
        float m_ = (float)(t_ > u_ ? t_ : u_);
        q1bf[(size_t)b*2880 + o] = bfbits(m_);
    }
}

// conv2 via bf16 MFMA implicit GEMM. One image per block. M=64 pos, N=64(50), K=20x32.
// + quantize + 2x2 pool -> q2bf[B][800] bf16 ints (k = co*16 + ph*4 + pw)
__global__ __launch_bounds__(TPB) void k_conv2(const ushort_t* q1bf, const ushort_t* w2bf,
                                               const float* ws, ushort_t* q2bf){
    __shared__ ushort_t xs[2880];
    __shared__ ushort_t Ab[2][64*40];
    int b = blockIdx.x, tid = threadIdx.x;
    int lane = tid & 63, wv = tid >> 6;
    int ln = lane & 15, quad = lane >> 4;
    int n0 = wv * 16;

    // load image (bf16 ints) coalesced as dwords
    const unsigned int* src32 = (const unsigned int*)(q1bf + (size_t)b*2880);
    unsigned int* xs32 = (unsigned int*)xs;
    for (int i = tid; i < 1440; i += TPB) xs32[i] = src32[i];
    // zero pad region k=25..31 of both im2col buffers
    for (int i = tid; i < 448; i += TPB){
        int p = i / 7, k = 25 + (i - 7*p);
        Ab[0][p*40 + k] = 0; Ab[1][p*40 + k] = 0;
    }
    // per-thread im2col offsets (ci-invariant)
    int dstoff[7], srcoff[7];
    #pragma unroll
    for (int t = 0; t < 7; ++t){
        int e = tid + t*TPB;
        if (e < 1600){
            int p = e / 25, k = e - 25*p;
            int kh = k / 5, kw = k - 5*kh;
            int oh = p >> 3, ow = p & 7;
            dstoff[t] = p*40 + k;
            srcoff[t] = (oh + kh)*12 + (ow + kw);
        } else dstoff[t] = -1;
    }
    __syncthreads();
    // build ci=0
    #pragma unroll
    for (int t = 0; t < 7; ++t)
        if (dstoff[t] >= 0) Ab[0][dstoff[t]] = xs[srcoff[t]];
    __syncthreads();

    floatx4 acc[4];
    #pragma unroll
    for (int mt = 0; mt < 4; ++mt) acc[mt] = (floatx4){0.f,0.f,0.f,0.f};

    for (int ci = 0; ci < 20; ++ci){
        const ushort_t* cur = &Ab[ci & 1][0];
        if (ci + 1 < 20){
            ushort_t* nxt = &Ab[(ci + 1) & 1][0];
            int base = (ci + 1) * 144;
            #pragma unroll
            for (int t = 0; t < 7; ++t)
                if (dstoff[t] >= 0) nxt[dstoff[t]] = xs[base + srcoff[t]];
        }
        ushort8 bw = *(const ushort8*)(w2bf + ci*2048 + (n0 + ln)*32 + quad*8);
        bf16x8 bfr = __builtin_bit_cast(bf16x8, bw);
        #pragma unroll
        for (int mt = 0; mt < 4; ++mt){
            ushort8 aw = *(const ushort8*)(cur + (16*mt + ln)*40 + quad*8);
            acc[mt] = __builtin_amdgcn_mfma_f32_16x16x32_bf16(
                          __builtin_bit_cast(bf16x8, aw), bfr, acc[mt], 0, 0, 0);
        }
        __syncthreads();
    }

    // epilogue: quantize each of 64 positions, then 2x2 pool, write bf16
    float sc2 = ws[0];
    int n = n0 + ln;
    float bias = (n < 50) ? ws[OFF_B2 + n] : 0.0f;
    #pragma unroll
    for (int mt = 0; mt < 4; ++mt){
        float q[4];
        #pragma unroll
        for (int r = 0; r < 4; ++r){
            float y = fmaxf((acc[mt][r] * sc2 + bias) / S_N2, 0.0f);
            q[r] = fmodf(rintf(y), 256.0f);
        }
        float h0 = fmaxf(q[0], q[1]), h1 = fmaxf(q[2], q[3]);
        float v0 = fmaxf(h0, __shfl_xor(h0, 32));
        float v1 = fmaxf(h1, __shfl_xor(h1, 32));
        if (quad < 2 && n < 50){
            size_t base = (size_t)b*800 + n*16 + mt*4 + quad*2;
            q2bf[base]     = bfbits(v0);
            q2bf[base + 1] = bfbits(v1);
        }
    }
}

// fc1 via bf16 MFMA GEMM: [B,800] x [512,800]^T, tile 64x64, K-chunk 32, dbuf LDS.
__global__ __launch_bounds__(TPB) void k_fc1(const ushort_t* q2bf, const ushort_t* w3bf,
                                             const float* ws, unsigned char* q3, int B){
    __shared__ ushort_t As[2][64*40];
    int tid = threadIdx.x;
    int n0b = blockIdx.x * 64;
    int b0  = blockIdx.y * 64;
    int lane = tid & 63, wv = tid >> 6;
    int ln = lane & 15, quad = lane >> 4;
    int n0 = n0b + wv*16;
    int lrow = tid >> 2, lk = (tid & 3) * 8;
    const ushort_t* asrc = q2bf + (size_t)(b0 + lrow)*800 + lk;
    ushort_t* adst0 = &As[0][0] + lrow*40 + lk;
    ushort_t* adst1 = &As[1][0] + lrow*40 + lk;

    floatx4 acc[4];
    #pragma unroll
    for (int mt = 0; mt < 4; ++mt) acc[mt] = (floatx4){0.f,0.f,0.f,0.f};

    // prologue: chunk 0
    *(ushort8*)adst0 = *(const ushort8*)asrc;
    __syncthreads();

    for (int c = 0; c < 25; ++c){
        const ushort_t* cur = &As[c & 1][0];
        ushort8 tn;
        bool pf = (c + 1 < 25);
        if (pf) tn = *(const ushort8*)(asrc + (c + 1)*32);
        ushort8 bw = *(const ushort8*)(w3bf + (size_t)(n0 + ln)*800 + c*32 + quad*8);
        bf16x8 bfr = __builtin_bit_cast(bf16x8, bw);
        #pragma unroll
        for (int mt = 0; mt < 4; ++mt){
            ushort8 aw = *(const ushort8*)(cur + (16*mt + ln)*40 + quad*8);
            acc[mt] = __builtin_amdgcn_mfma_f32_16x16x32_bf16(
                          __builtin_bit_cast(bf16x8, aw), bfr, acc[mt], 0, 0, 0);
        }
        if (pf) *(ushort8*)(((c + 1) & 1) ? adst1 : adst0) = tn;
        __syncthreads();
    }

    float sc3 = ws[1];
    int n = n0 + ln;
    if (n < 500){
        float bias = ws[OFF_B3 + n];
        #pragma unroll
        for (int mt = 0; mt < 4; ++mt){
            #pragma unroll
            for (int r = 0; r < 4; ++r){
                int m = 16*mt + 4*quad + r;
                float y = fmaxf((acc[mt][r] * sc3 + bias) / S_N3, 0.0f);
                float q = fmodf(rintf(y), 256.0f);
                q3[(size_t)(b0 + m)*500 + n] = (unsigned char)q;
            }
        }
    }
}

// fc2 (dequant + [B,500]x[10,500]^T + bias) + log_softmax. 16 rows/block, w2 in LDS.
__global__ __launch_bounds__(TPB) void k_fc2(const unsigned char* q3, const float* w2,
                                             const float* b2, float* out, int B){
    __shared__ float w2s[5000];
    __shared__ float b2s[10];
    int tid = threadIdx.x;
    for (int i = tid; i < 5000; i += TPB) w2s[i] = w2[i];
    if (tid < 10) b2s[tid] = b2[tid];
    __syncthreads();
    int lane = tid & 63, wv = tid >> 6;
    for (int rr = 0; rr < 4; ++rr){
        int b = blockIdx.x*16 + wv*4 + rr;
        if (b >= B) break;
        float acc[10];
        #pragma unroll
        for (int c = 0; c < 10; ++c) acc[c] = 0.0f;
        for (int k = lane; k < 500; k += 64){
            float xf = S_N3 * (float)q3[(size_t)b*500 + k];
            #pragma unroll
            for (int c = 0; c < 10; ++c)
                acc[c] = fmaf(xf, w2s[c*500 + k], acc[c]);
        }
        #pragma unroll
        for (int off = 32; off > 0; off >>= 1)
            #pragma unroll
            for (int c = 0; c < 10; ++c)
                acc[c] += __shfl_xor(acc[c], off);
        float lg[10], m = -INFINITY;
        #pragma unroll
        for (int c = 0; c < 10; ++c){ lg[c] = acc[c] + b2s[c]; m = fmaxf(m, lg[c]); }
        float sum = 0.0f;
        #pragma unroll
        for (int c = 0; c < 10; ++c) sum += expf(lg[c] - m);
        float ls = logf(sum);
        if (lane < 10) out[(size_t)b*10 + lane] = lg[lane] - m - ls;
    }
}

extern "C" void kernel_launch(void* const* d_in, const int* in_sizes, int n_in,
                              void* d_out, int out_size, void* d_ws, size_t ws_size,
                              hipStream_t stream){
    const float* x   = (const float*)d_in[0];
    const float* c1w = (const float*)d_in[1];
    const float* c1b = (const float*)d_in[2];
    const float* c2w = (const float*)d_in[3];
    const float* c2b = (const float*)d_in[4];
    const float* f1w = (const float*)d_in[5];
    const float* f1b = (const float*)d_in[6];
    const float* f2w = (const float*)d_in[7];
    const float* f2b = (const float*)d_in[8];
    int B = in_sizes[0] / 784;

    float* ws = (float*)d_ws;
    unsigned int* enc = (unsigned int*)d_ws + 4;
    ushort_t* w1bf = (ushort_t*)((char*)d_ws + W1BF_BYTE);
    ushort_t* w2bf = (ushort_t*)((char*)d_ws + W2BF_BYTE);
    ushort_t* w3bf = (ushort_t*)((char*)d_ws + W3BF_BYTE);
    ushort_t* q1bf = (ushort_t*)((char*)d_ws + Q1_BYTE);
    ushort_t* q2bf = (ushort_t*)((char*)d_ws + Q2_BYTE);
    unsigned char* q3 = (unsigned char*)d_ws + Q3_BYTE;
    float* out = (float*)d_out;

    k_init<<<1, 64, 0, stream>>>(enc);
    k_minmax<<<72, TPB, 0, stream>>>(c1w, c1b, c2w, c2b, f1w, f1b, enc);
    k_make_eff<<<(N_EFF + TPB - 1)/TPB, TPB, 0, stream>>>(c1w, c1b, c2w, c2b, f1w, f1b, enc, ws, w1bf, w2bf, w3bf);
    k_conv1<<<B, TPB, 0, stream>>>(x, w1bf, ws, q1bf);
    k_conv2<<<B, TPB, 0, stream>>>(q1bf, w2bf, ws, q2bf);
    dim3 g_fc1(8, B/64);
    k_fc1<<<g_fc1, TPB, 0, stream>>>(q2bf, w3bf, ws, q3, B);
    k_fc2<<<(B + 15)/16, TPB, 0, stream>>>(q3, f2w, f2b, out, B);
}